// Round 14
// baseline (149.817 us; speedup 1.0000x reference)
//
#include <hip/hip_runtime.h>

#define H 32
#define NSEG 1000      // phase-1 segments/blocks
#define RBITS 9
#define RANGE 512      // nodes per bucket = 1<<RBITS
#define SPLIT 4        // phase-2 blocks per bucket
#define SEGPER (NSEG / SPLIT)
#define MAXROWS 260    // max buckets+1 (parallel scan needs nbuk <= 256)
#define EBMAX 6400     // max edges per segment stageable in LDS

typedef __attribute__((ext_vector_type(2))) __fp16 half2v;
typedef __attribute__((ext_vector_type(8))) __fp16 half8;
typedef __attribute__((ext_vector_type(4))) float f32x4;
typedef unsigned int u32;
typedef unsigned short u16;

union HU { int i[4]; half8 h; };

static __device__ __forceinline__ int pkrtz(float a, float b) {
    return __builtin_bit_cast(int, __builtin_amdgcn_cvt_pkrtz(a, b));
}

// ---- per-edge MLP: ALL THREE layers via MFMA ----
// Layer-1 trick: D-fragment rows (4g+r / 16+4g+r) == layer-2 B-fragment
// k-slices (klo=4g, khi=16+4g), so relu(D1)+pack feeds MFMA-2 directly.
struct Invar {
    half8 a1frag[2];              // layer-1 A: W1 on k-rows 0,1 (g==0 lanes only)
    f32x4 c1a, c1b;               // b1 slices as MFMA-1 C operand
    half8 afrag[2];               // layer-2 A: W2^T fragments
    f32x4 c0, c1;                 // b2 slices as MFMA-2 C operand
    float w3lo[4], w3hi[4];
    float b3v;
};

static __device__ __forceinline__ void load_invar(
    Invar& v, int g, int col,
    const float* __restrict__ W1, const float* __restrict__ b1,
    const float* __restrict__ W2, const float* __restrict__ b2,
    const float* __restrict__ W3, const float* __restrict__ b3)
{
    const int klo = 4 * g, khi = 16 + 4 * g;
    // layer-1 A fragments: A[j][0]=W1[0][j], A[j][1]=W1[1][j]; rows j=mt*16+col.
    // Only g==0 lanes hold k-slice containing k=0,1 (elem0 pair); others zero.
#pragma unroll
    for (int mt = 0; mt < 2; ++mt) {
        HU ua;
        const int j = mt * 16 + col;
        ua.i[0] = (g == 0) ? pkrtz(W1[j], W1[H + j]) : 0;
        ua.i[1] = 0; ua.i[2] = 0; ua.i[3] = 0;
        v.a1frag[mt] = ua.h;
    }
#pragma unroll
    for (int r = 0; r < 4; ++r) {
        v.c1a[r] = b1[klo + r]; v.c1b[r] = b1[khi + r];
    }
#pragma unroll
    for (int mt = 0; mt < 2; ++mt) {
        HU ua;
        const int c = mt * 16 + col;
        ua.i[0] = pkrtz(W2[(klo + 0) * H + c], W2[(klo + 1) * H + c]);
        ua.i[1] = pkrtz(W2[(klo + 2) * H + c], W2[(klo + 3) * H + c]);
        ua.i[2] = pkrtz(W2[(khi + 0) * H + c], W2[(khi + 1) * H + c]);
        ua.i[3] = pkrtz(W2[(khi + 2) * H + c], W2[(khi + 3) * H + c]);
        v.afrag[mt] = ua.h;
    }
#pragma unroll
    for (int r = 0; r < 4; ++r) {
        v.c0[r] = b2[klo + r]; v.c1[r] = b2[khi + r];
        v.w3lo[r] = W3[klo + r]; v.w3hi[r] = W3[khi + r];
    }
    v.b3v = b3[0];
}

static __device__ __forceinline__ float edge_w(const Invar& v, int g, int col, int abpk)
{
    float wred0 = 0.f, wred1 = 0.f, wred2 = 0.f, wred3 = 0.f;
#pragma unroll
    for (int T = 0; T < 4; ++T) {
        const int abT = __builtin_amdgcn_ds_bpermute(((T << 4) + col) << 2, abpk);

        // layer 1 via MFMA: B[0][e]=a, B[1][e]=b (g==0 lanes), C=b1
        HU ub1;
        ub1.i[0] = (g == 0) ? abT : 0;
        ub1.i[1] = 0; ub1.i[2] = 0; ub1.i[3] = 0;
        f32x4 d0 = __builtin_amdgcn_mfma_f32_16x16x32_f16(v.a1frag[0], ub1.h, v.c1a, 0, 0, 0);
        f32x4 d1 = __builtin_amdgcn_mfma_f32_16x16x32_f16(v.a1frag[1], ub1.h, v.c1b, 0, 0, 0);

        // relu + pack: D rows ARE this lane's layer-2 k-slice
        HU ub;
        ub.i[0] = pkrtz(fmaxf(d0[0], 0.f), fmaxf(d0[1], 0.f));
        ub.i[1] = pkrtz(fmaxf(d0[2], 0.f), fmaxf(d0[3], 0.f));
        ub.i[2] = pkrtz(fmaxf(d1[0], 0.f), fmaxf(d1[1], 0.f));
        ub.i[3] = pkrtz(fmaxf(d1[2], 0.f), fmaxf(d1[3], 0.f));

        f32x4 acc0 = __builtin_amdgcn_mfma_f32_16x16x32_f16(v.afrag[0], ub.h, v.c0, 0, 0, 0);
        f32x4 acc1 = __builtin_amdgcn_mfma_f32_16x16x32_f16(v.afrag[1], ub.h, v.c1, 0, 0, 0);

        float p = 0.f;
#pragma unroll
        for (int r = 0; r < 4; ++r) {
            p += fmaxf(acc0[r], 0.f) * v.w3lo[r];
            p += fmaxf(acc1[r], 0.f) * v.w3hi[r];
        }
        p += __shfl_xor(p, 16, 64);
        p += __shfl_xor(p, 32, 64);
        const float wt = p + v.b3v;
        if      (T == 0) wred0 = wt;
        else if (T == 1) wred1 = wt;
        else if (T == 2) wred2 = wt;
        else             wred3 = wt;
    }
    const float wa = (g & 1) ? wred1 : wred0;
    const float wb = (g & 1) ? wred3 : wred2;
    return (g & 2) ? wb : wa;
}

// ---------------- xu interleave prep ----------------
__global__ void xu_pack_kernel(const float* __restrict__ x, const float* __restrict__ u,
                               float2* __restrict__ xu, int n) {
    int i = blockIdx.x * 256 + threadIdx.x;
    if (i < n) xu[i] = make_float2(x[i], u[i]);
}

// ---------------- phase 1 ----------------
__global__ __launch_bounds__(256) void p1_kernel(
    const float* __restrict__ x,
    const int*   __restrict__ ei,
    const float2* __restrict__ xu,
    const float* __restrict__ W1, const float* __restrict__ b1,
    const float* __restrict__ W2, const float* __restrict__ b2,
    const float* __restrict__ W3, const float* __restrict__ b3,
    u32* __restrict__ pairs, u32* __restrict__ offs,
    int E, int Eb, int nbuk)
{
    __shared__ u32 cnt[MAXROWS];
    __shared__ u32 cur[MAXROWS];
    __shared__ u32 wsum[4];
    __shared__ u32 lds_pairs[EBMAX];
    const int tid  = threadIdx.x;
    const int lane = tid & 63;
    const int wv   = tid >> 6;
    const int g    = lane >> 4;
    const int col  = lane & 15;
    const int b    = blockIdx.x;

    const int slice0 = b * Eb;
    int sliceN = E - slice0;
    if (sliceN < 0) sliceN = 0;
    if (sliceN > Eb) sliceN = Eb;

    Invar v;
    load_invar(v, g, col, W1, b1, W2, b2, W3, b3);

    for (int k = tid; k <= nbuk; k += 256) cnt[k] = 0;
    __syncthreads();
    if (((slice0 & 3) == 0) && ((sliceN & 3) == 0)) {
        const uint4* e4 = (const uint4*)(ei + slice0);
        const int n4 = sliceN >> 2;
        for (int i = tid; i < n4; i += 256) {
            const uint4 s4 = e4[i];
            atomicAdd(&cnt[s4.x >> RBITS], 1u);
            atomicAdd(&cnt[s4.y >> RBITS], 1u);
            atomicAdd(&cnt[s4.z >> RBITS], 1u);
            atomicAdd(&cnt[s4.w >> RBITS], 1u);
        }
    } else {
        for (int i = tid; i < sliceN; i += 256)
            atomicAdd(&cnt[((u32)ei[slice0 + i]) >> RBITS], 1u);
    }
    __syncthreads();

    // parallel exclusive scan over nbuk (<=256) bins
    {
        const u32 myc = (tid < nbuk) ? cnt[tid] : 0;
        u32 val = myc;
#pragma unroll
        for (int d = 1; d < 64; d <<= 1) {
            const u32 t = __shfl_up(val, d, 64);
            if (lane >= d) val += t;
        }
        if (lane == 63) wsum[wv] = val;
        __syncthreads();
        u32 woff = 0;
#pragma unroll
        for (int w = 0; w < 4; ++w) if (w < wv) woff += wsum[w];
        val += woff;
        if (tid < nbuk) cur[tid] = val - myc;
        if (tid == 0)   cur[nbuk] = wsum[0] + wsum[1] + wsum[2] + wsum[3];
    }
    __syncthreads();
    for (int k = tid; k <= nbuk; k += 256) offs[(size_t)b * (nbuk + 1) + k] = cur[k];
    __syncthreads();

    // pass B: MLP + bucket-sorted scatter into LDS; 4 groups per wave-iteration
    const int nbfull = sliceN >> 6;
    const int nquad  = nbfull >> 2;
    for (int q = wv; q < nquad; q += 4) {
        const int e0 = slice0 + (q << 8) + lane;
        const int e1 = e0 + 64, e2 = e0 + 128, e3 = e0 + 192;
        const int src0 = ei[e0],     src1 = ei[e1],     src2 = ei[e2],     src3 = ei[e3];
        const int dst0 = ei[E + e0], dst1 = ei[E + e1], dst2 = ei[E + e2], dst3 = ei[E + e3];
        const float  x0  = x[src0],  x1  = x[src1],  x2  = x[src2],  x3  = x[src3];
        const float2 xd0 = xu[dst0], xd1 = xu[dst1], xd2 = xu[dst2], xd3 = xu[dst3];

        const float w0 = edge_w(v, g, col, pkrtz(x0, xd0.x));
        const float w1 = edge_w(v, g, col, pkrtz(x1, xd1.x));
        const float w2 = edge_w(v, g, col, pkrtz(x2, xd2.x));
        const float w3 = edge_w(v, g, col, pkrtz(x3, xd3.x));

        const u32 pos0 = atomicAdd(&cur[((u32)src0) >> RBITS], 1u);
        lds_pairs[pos0] = ((u32)(u16)pkrtz(w0 * xd0.y, 0.0f)) | (((u32)src0 & (RANGE - 1)) << 16);
        const u32 pos1 = atomicAdd(&cur[((u32)src1) >> RBITS], 1u);
        lds_pairs[pos1] = ((u32)(u16)pkrtz(w1 * xd1.y, 0.0f)) | (((u32)src1 & (RANGE - 1)) << 16);
        const u32 pos2 = atomicAdd(&cur[((u32)src2) >> RBITS], 1u);
        lds_pairs[pos2] = ((u32)(u16)pkrtz(w2 * xd2.y, 0.0f)) | (((u32)src2 & (RANGE - 1)) << 16);
        const u32 pos3 = atomicAdd(&cur[((u32)src3) >> RBITS], 1u);
        lds_pairs[pos3] = ((u32)(u16)pkrtz(w3 * xd3.y, 0.0f)) | (((u32)src3 & (RANGE - 1)) << 16);
    }
    const int nbany = (sliceN + 63) >> 6;
    for (int bi = (nquad << 2) + wv; bi < nbany; bi += 4) {
        const int loc = (bi << 6) + lane;
        const bool valid = loc < sliceN;
        const int eL = slice0 + (valid ? loc : 0);
        const int src = ei[eL];
        const int dst = ei[E + eL];
        const float2 xud = xu[dst];
        const int abpk = pkrtz(x[src], xud.x);
        const float we = edge_w(v, g, col, abpk);
        if (valid) {
            const int buk = ((u32)src) >> RBITS;
            const u32 pos = atomicAdd(&cur[buk], 1u);
            lds_pairs[pos] = ((u32)(u16)pkrtz(we * xud.y, 0.0f)) | (((u32)src & (RANGE - 1)) << 16);
        }
    }
    __syncthreads();

    const int n4 = sliceN >> 2;
    const uint4* lp4 = (const uint4*)lds_pairs;
    uint4* gp4 = (uint4*)(pairs + slice0);
    for (int i = tid; i < n4; i += 256) gp4[i] = lp4[i];
    for (int i = (n4 << 2) + tid; i < sliceN; i += 256) pairs[slice0 + i] = lds_pairs[i];
}

// ---------------- phase 2: flat-indexed per-bucket LDS accumulate ----------------
__global__ __launch_bounds__(256) void p2_kernel(
    const u32* __restrict__ pairs, const u32* __restrict__ offs,
    float* __restrict__ pf, int Eb, int nbuk)
{
    __shared__ float acc[RANGE];
    __shared__ u32 so_l[SEGPER];
    __shared__ u32 pre[SEGPER + 1];
    __shared__ u32 wsum[4];
    const int tid = threadIdx.x;
    const int lane = tid & 63;
    const int wv  = tid >> 6;
    const int buk = blockIdx.x / SPLIT;
    const int sp  = blockIdx.x % SPLIT;

    acc[tid] = 0.f;
    acc[tid + 256] = 0.f;
    u32 myc = 0, so = 0;
    if (tid < SEGPER) {
        const int s = sp + tid * SPLIT;
        const u32* o = offs + (size_t)s * (nbuk + 1) + buk;
        so = o[0];
        myc = o[1] - so;
    }
    {
        u32 val = myc;
#pragma unroll
        for (int d = 1; d < 64; d <<= 1) {
            const u32 t = __shfl_up(val, d, 64);
            if (lane >= d) val += t;
        }
        if (lane == 63) wsum[wv] = val;
        __syncthreads();
        u32 woff = 0;
#pragma unroll
        for (int w = 0; w < 4; ++w) if (w < wv) woff += wsum[w];
        val += woff;
        if (tid < SEGPER) { so_l[tid] = so; pre[tid + 1] = val; }
        if (tid == 0) pre[0] = 0;
    }
    __syncthreads();

    const int total = (int)pre[SEGPER];
    for (int base = tid << 1; base < total; base += 512) {
#pragma unroll
        for (int k = 0; k < 2; ++k) {
            const int i = base + k;
            if (i >= total) break;
            int lo = 0, hi = SEGPER;
            while (hi - lo > 1) {
                const int mid = (lo + hi) >> 1;
                if (pre[mid] <= (u32)i) lo = mid; else hi = mid;
            }
            const int s = sp + lo * SPLIT;
            const u32 p = pairs[(size_t)s * Eb + so_l[lo] + (u32)i - pre[lo]];
            const float val = (float)__builtin_bit_cast(_Float16, (u16)(p & 0xffffu));
            atomicAdd(&acc[p >> 16], val);
        }
    }
    __syncthreads();

    const size_t stride = (size_t)nbuk * RANGE;
    const int node0 = buk * RANGE;
    pf[(size_t)sp * stride + node0 + tid] = acc[tid];
    pf[(size_t)sp * stride + node0 + tid + 256] = acc[tid + 256];
}

__global__ void freduce_kernel(const float* __restrict__ pf, float* __restrict__ f,
                               int n, int stride) {
    const int i = blockIdx.x * 256 + threadIdx.x;
    if (i >= n) return;
    float s = 0.f;
#pragma unroll
    for (int r = 0; r < SPLIT; ++r) s += pf[(size_t)r * stride + i];
    f[i] = s;
}

// ---------------- fallback: direct-atomic path ----------------
__global__ void zero_kernel(float* __restrict__ p, int n) {
    int i = blockIdx.x * blockDim.x + threadIdx.x;
    if (i < n) p[i] = 0.0f;
}

__global__ __launch_bounds__(256) void fb_kernel(
    const float* __restrict__ x,
    const int*   __restrict__ ei,
    const float* __restrict__ u,
    const float* __restrict__ W1, const float* __restrict__ b1,
    const float* __restrict__ W2, const float* __restrict__ b2,
    const float* __restrict__ W3, const float* __restrict__ b3,
    float* __restrict__ f, int E)
{
    const int lane = threadIdx.x & 63;
    const int g    = lane >> 4;
    const int col  = lane & 15;

    Invar v;
    load_invar(v, g, col, W1, b1, W2, b2, W3, b3);

    const int nbatch = E >> 6;
    const int gw = blockIdx.x * 4 + (threadIdx.x >> 6);
    const int nw = gridDim.x * 4;
    for (int bt = gw; bt < nbatch; bt += nw) {
        const int e   = (bt << 6) + lane;
        const int src = ei[e];
        const int dst = ei[E + e];
        const int abpk = pkrtz(x[src], x[dst]);
        const float ud = u[dst];
        const float we = edge_w(v, g, col, abpk);
        atomicAdd(&f[src], we * ud);
    }
}

extern "C" void kernel_launch(void* const* d_in, const int* in_sizes, int n_in,
                              void* d_out, int out_size, void* d_ws, size_t ws_size,
                              hipStream_t stream) {
    const float* x  = (const float*)d_in[0];
    const int*   ei = (const int*)d_in[1];
    const float* u  = (const float*)d_in[2];
    const float* W1 = (const float*)d_in[3];
    const float* b1 = (const float*)d_in[4];
    const float* W2 = (const float*)d_in[5];
    const float* b2 = (const float*)d_in[6];
    const float* W3 = (const float*)d_in[7];
    const float* b3 = (const float*)d_in[8];
    float* f = (float*)d_out;

    const int n = in_sizes[0];
    const int E = in_sizes[1] / 2;

    const int nbuk = (n + RANGE - 1) / RANGE;
    const int Eb = (((E + NSEG - 1) / NSEG) + 63) & ~63;
    const size_t stride = (size_t)nbuk * RANGE;
    const size_t need = ((size_t)NSEG * Eb + (size_t)(nbuk + 1) * NSEG + (size_t)SPLIT * stride)
                        * sizeof(u32);
    const bool xu_fits = (size_t)SPLIT * stride * sizeof(float) >= (size_t)n * sizeof(float2);

    if (nbuk + 1 <= MAXROWS && nbuk <= 256 && Eb <= EBMAX && ws_size >= need
        && (E & 63) == 0 && xu_fits) {
        u32* pairs = (u32*)d_ws;
        u32* offs  = pairs + (size_t)NSEG * Eb;
        float* pf  = (float*)(offs + (size_t)(nbuk + 1) * NSEG);
        float2* xu = (float2*)pf;   // alias: xu dead before p2 writes pf

        xu_pack_kernel<<<(n + 255) / 256, 256, 0, stream>>>(x, u, xu, n);
        p1_kernel<<<NSEG, 256, 0, stream>>>(x, ei, xu, W1, b1, W2, b2, W3, b3,
                                            pairs, offs, E, Eb, nbuk);
        p2_kernel<<<nbuk * SPLIT, 256, 0, stream>>>(pairs, offs, pf, Eb, nbuk);
        freduce_kernel<<<(n + 255) / 256, 256, 0, stream>>>(pf, f, n, (int)stride);
    } else {
        zero_kernel<<<(n + 255) / 256, 256, 0, stream>>>(f, n);
        fb_kernel<<<2048, 256, 0, stream>>>(x, ei, u, W1, b1, W2, b2, W3, b3, f, E);
    }
}

// Round 15
// 134.967 us; speedup vs baseline: 1.1100x; 1.1100x over previous
//
#include <hip/hip_runtime.h>

#define H 32
#define NSEG 1000      // phase-1 segments/blocks
#define RBITS 9
#define RANGE 512      // nodes per bucket = 1<<RBITS
#define SPLIT 10       // phase-2 blocks per bucket
#define SEGPER (NSEG / SPLIT)
#define MAXROWS 260    // max buckets+1 (parallel scan needs nbuk <= 256)
#define EBMAX 6400     // max edges per segment stageable in LDS

typedef __attribute__((ext_vector_type(2))) __fp16 half2v;
typedef __attribute__((ext_vector_type(8))) __fp16 half8;
typedef __attribute__((ext_vector_type(4))) float f32x4;
typedef unsigned int u32;
typedef unsigned short u16;

union HU { int i[4]; half8 h; };

static __device__ __forceinline__ int pkrtz(float a, float b) {
    return __builtin_bit_cast(int, __builtin_amdgcn_cvt_pkrtz(a, b));
}

static __device__ __forceinline__ float fdot2f(int w, int ab, float c) {
    return __builtin_amdgcn_fdot2(__builtin_bit_cast(half2v, w),
                                  __builtin_bit_cast(half2v, ab), c, false);
}

// ---- verified per-edge MLP (R12 structure: fdot2 layer1, MFMA layer2) ----
struct Invar {
    int   w1p[8];
    float b1v[8];
    half8 afrag[2];
    f32x4 c0, c1;                 // b2 slices as MFMA C operand
    float w3lo[4], w3hi[4];
    float b3v;
};

static __device__ __forceinline__ void load_invar(
    Invar& v, int g, int col,
    const float* __restrict__ W1, const float* __restrict__ b1,
    const float* __restrict__ W2, const float* __restrict__ b2,
    const float* __restrict__ W3, const float* __restrict__ b3)
{
    const int klo = 4 * g, khi = 16 + 4 * g;
#pragma unroll
    for (int i = 0; i < 4; ++i) {
        v.w1p[i]     = pkrtz(W1[klo + i], W1[H + klo + i]);
        v.w1p[4 + i] = pkrtz(W1[khi + i], W1[H + khi + i]);
        v.b1v[i]     = b1[klo + i];
        v.b1v[4 + i] = b1[khi + i];
    }
#pragma unroll
    for (int mt = 0; mt < 2; ++mt) {
        HU ua;
        const int c = mt * 16 + col;
        ua.i[0] = pkrtz(W2[(klo + 0) * H + c], W2[(klo + 1) * H + c]);
        ua.i[1] = pkrtz(W2[(klo + 2) * H + c], W2[(klo + 3) * H + c]);
        ua.i[2] = pkrtz(W2[(khi + 0) * H + c], W2[(khi + 1) * H + c]);
        ua.i[3] = pkrtz(W2[(khi + 2) * H + c], W2[(khi + 3) * H + c]);
        v.afrag[mt] = ua.h;
    }
#pragma unroll
    for (int r = 0; r < 4; ++r) {
        v.c0[r] = b2[klo + r]; v.c1[r] = b2[khi + r];
        v.w3lo[r] = W3[klo + r]; v.w3hi[r] = W3[khi + r];
    }
    v.b3v = b3[0];
}

static __device__ __forceinline__ float edge_w(const Invar& v, int g, int col, int abpk)
{
    float wred0 = 0.f, wred1 = 0.f, wred2 = 0.f, wred3 = 0.f;
#pragma unroll
    for (int T = 0; T < 4; ++T) {
        const int abT = __builtin_amdgcn_ds_bpermute(((T << 4) + col) << 2, abpk);
        const float h0 = fmaxf(fdot2f(v.w1p[0], abT, v.b1v[0]), 0.f);
        const float h1 = fmaxf(fdot2f(v.w1p[1], abT, v.b1v[1]), 0.f);
        const float h2 = fmaxf(fdot2f(v.w1p[2], abT, v.b1v[2]), 0.f);
        const float h3 = fmaxf(fdot2f(v.w1p[3], abT, v.b1v[3]), 0.f);
        const float h4 = fmaxf(fdot2f(v.w1p[4], abT, v.b1v[4]), 0.f);
        const float h5 = fmaxf(fdot2f(v.w1p[5], abT, v.b1v[5]), 0.f);
        const float h6 = fmaxf(fdot2f(v.w1p[6], abT, v.b1v[6]), 0.f);
        const float h7 = fmaxf(fdot2f(v.w1p[7], abT, v.b1v[7]), 0.f);

        HU ub;
        ub.i[0] = pkrtz(h0, h1);
        ub.i[1] = pkrtz(h2, h3);
        ub.i[2] = pkrtz(h4, h5);
        ub.i[3] = pkrtz(h6, h7);

        f32x4 acc0 = __builtin_amdgcn_mfma_f32_16x16x32_f16(v.afrag[0], ub.h, v.c0, 0, 0, 0);
        f32x4 acc1 = __builtin_amdgcn_mfma_f32_16x16x32_f16(v.afrag[1], ub.h, v.c1, 0, 0, 0);

        float p = 0.f;
#pragma unroll
        for (int r = 0; r < 4; ++r) {
            p += fmaxf(acc0[r], 0.f) * v.w3lo[r];
            p += fmaxf(acc1[r], 0.f) * v.w3hi[r];
        }
        p += __shfl_xor(p, 16, 64);
        p += __shfl_xor(p, 32, 64);
        const float wt = p + v.b3v;
        if      (T == 0) wred0 = wt;
        else if (T == 1) wred1 = wt;
        else if (T == 2) wred2 = wt;
        else             wred3 = wt;
    }
    const float wa = (g & 1) ? wred1 : wred0;
    const float wb = (g & 1) ? wred3 : wred2;
    return (g & 2) ? wb : wa;
}

// ---------------- xu interleave prep ----------------
__global__ void xu_pack_kernel(const float* __restrict__ x, const float* __restrict__ u,
                               float2* __restrict__ xu, int n) {
    int i = blockIdx.x * 256 + threadIdx.x;
    if (i < n) xu[i] = make_float2(x[i], u[i]);
}

// ---------------- phase 1 ----------------
__global__ __launch_bounds__(256) void p1_kernel(
    const float* __restrict__ x,
    const int*   __restrict__ ei,
    const float2* __restrict__ xu,
    const float* __restrict__ W1, const float* __restrict__ b1,
    const float* __restrict__ W2, const float* __restrict__ b2,
    const float* __restrict__ W3, const float* __restrict__ b3,
    u32* __restrict__ pairs, u32* __restrict__ offs,
    int E, int Eb, int nbuk)
{
    __shared__ u32 cnt[MAXROWS];
    __shared__ u32 cur[MAXROWS];
    __shared__ u32 wsum[4];
    __shared__ u32 lds_pairs[EBMAX];
    const int tid  = threadIdx.x;
    const int lane = tid & 63;
    const int wv   = tid >> 6;
    const int g    = lane >> 4;
    const int col  = lane & 15;
    const int b    = blockIdx.x;

    const int slice0 = b * Eb;
    int sliceN = E - slice0;
    if (sliceN < 0) sliceN = 0;
    if (sliceN > Eb) sliceN = Eb;

    Invar v;
    load_invar(v, g, col, W1, b1, W2, b2, W3, b3);

    for (int k = tid; k <= nbuk; k += 256) cnt[k] = 0;
    __syncthreads();
    if (((slice0 & 3) == 0) && ((sliceN & 3) == 0)) {
        const uint4* e4 = (const uint4*)(ei + slice0);
        const int n4 = sliceN >> 2;
        for (int i = tid; i < n4; i += 256) {
            const uint4 s4 = e4[i];
            atomicAdd(&cnt[s4.x >> RBITS], 1u);
            atomicAdd(&cnt[s4.y >> RBITS], 1u);
            atomicAdd(&cnt[s4.z >> RBITS], 1u);
            atomicAdd(&cnt[s4.w >> RBITS], 1u);
        }
    } else {
        for (int i = tid; i < sliceN; i += 256)
            atomicAdd(&cnt[((u32)ei[slice0 + i]) >> RBITS], 1u);
    }
    __syncthreads();

    // parallel exclusive scan over nbuk (<=256) bins
    {
        const u32 myc = (tid < nbuk) ? cnt[tid] : 0;
        u32 val = myc;
#pragma unroll
        for (int d = 1; d < 64; d <<= 1) {
            const u32 t = __shfl_up(val, d, 64);
            if (lane >= d) val += t;
        }
        if (lane == 63) wsum[wv] = val;
        __syncthreads();
        u32 woff = 0;
#pragma unroll
        for (int w = 0; w < 4; ++w) if (w < wv) woff += wsum[w];
        val += woff;
        if (tid < nbuk) cur[tid] = val - myc;
        if (tid == 0)   cur[nbuk] = wsum[0] + wsum[1] + wsum[2] + wsum[3];
    }
    __syncthreads();
    // coalesced offs write: per-segment-contiguous layout offs[b*(nbuk+1)+k]
    for (int k = tid; k <= nbuk; k += 256) offs[(size_t)b * (nbuk + 1) + k] = cur[k];
    __syncthreads();

    // pass B: MLP + bucket-sorted scatter into LDS; 4 groups per wave-iteration
    const int nbfull = sliceN >> 6;
    const int nquad  = nbfull >> 2;
    for (int q = wv; q < nquad; q += 4) {
        const int e0 = slice0 + (q << 8) + lane;
        const int e1 = e0 + 64, e2 = e0 + 128, e3 = e0 + 192;
        const int src0 = ei[e0],     src1 = ei[e1],     src2 = ei[e2],     src3 = ei[e3];
        const int dst0 = ei[E + e0], dst1 = ei[E + e1], dst2 = ei[E + e2], dst3 = ei[E + e3];
        const float  x0  = x[src0],  x1  = x[src1],  x2  = x[src2],  x3  = x[src3];
        const float2 xd0 = xu[dst0], xd1 = xu[dst1], xd2 = xu[dst2], xd3 = xu[dst3];

        const float w0 = edge_w(v, g, col, pkrtz(x0, xd0.x));
        const float w1 = edge_w(v, g, col, pkrtz(x1, xd1.x));
        const float w2 = edge_w(v, g, col, pkrtz(x2, xd2.x));
        const float w3 = edge_w(v, g, col, pkrtz(x3, xd3.x));

        const u32 pos0 = atomicAdd(&cur[((u32)src0) >> RBITS], 1u);
        lds_pairs[pos0] = ((u32)(u16)pkrtz(w0 * xd0.y, 0.0f)) | (((u32)src0 & (RANGE - 1)) << 16);
        const u32 pos1 = atomicAdd(&cur[((u32)src1) >> RBITS], 1u);
        lds_pairs[pos1] = ((u32)(u16)pkrtz(w1 * xd1.y, 0.0f)) | (((u32)src1 & (RANGE - 1)) << 16);
        const u32 pos2 = atomicAdd(&cur[((u32)src2) >> RBITS], 1u);
        lds_pairs[pos2] = ((u32)(u16)pkrtz(w2 * xd2.y, 0.0f)) | (((u32)src2 & (RANGE - 1)) << 16);
        const u32 pos3 = atomicAdd(&cur[((u32)src3) >> RBITS], 1u);
        lds_pairs[pos3] = ((u32)(u16)pkrtz(w3 * xd3.y, 0.0f)) | (((u32)src3 & (RANGE - 1)) << 16);
    }
    const int nbany = (sliceN + 63) >> 6;
    for (int bi = (nquad << 2) + wv; bi < nbany; bi += 4) {
        const int loc = (bi << 6) + lane;
        const bool valid = loc < sliceN;
        const int eL = slice0 + (valid ? loc : 0);
        const int src = ei[eL];
        const int dst = ei[E + eL];
        const float2 xud = xu[dst];
        const int abpk = pkrtz(x[src], xud.x);
        const float we = edge_w(v, g, col, abpk);
        if (valid) {
            const int buk = ((u32)src) >> RBITS;
            const u32 pos = atomicAdd(&cur[buk], 1u);
            lds_pairs[pos] = ((u32)(u16)pkrtz(we * xud.y, 0.0f)) | (((u32)src & (RANGE - 1)) << 16);
        }
    }
    __syncthreads();

    const int n4 = sliceN >> 2;
    const uint4* lp4 = (const uint4*)lds_pairs;
    uint4* gp4 = (uint4*)(pairs + slice0);
    for (int i = tid; i < n4; i += 256) gp4[i] = lp4[i];
    for (int i = (n4 << 2) + tid; i < sliceN; i += 256) pairs[slice0 + i] = lds_pairs[i];
}

// ---------------- phase 2: flat-indexed per-bucket LDS accumulate ----------------
__global__ __launch_bounds__(256) void p2_kernel(
    const u32* __restrict__ pairs, const u32* __restrict__ offs,
    float* __restrict__ pf, int Eb, int nbuk)
{
    __shared__ float acc[RANGE];
    __shared__ u32 so_l[SEGPER];
    __shared__ u32 pre[SEGPER + 1];
    __shared__ u32 wsum[4];
    const int tid = threadIdx.x;
    const int lane = tid & 63;
    const int wv  = tid >> 6;
    const int buk = blockIdx.x / SPLIT;
    const int sp  = blockIdx.x % SPLIT;

    acc[tid] = 0.f;
    acc[tid + 256] = 0.f;
    u32 myc = 0, so = 0;
    if (tid < SEGPER) {
        const int s = sp + tid * SPLIT;
        const u32* o = offs + (size_t)s * (nbuk + 1) + buk;
        so = o[0];
        myc = o[1] - so;
    }
    {
        u32 val = myc;
#pragma unroll
        for (int d = 1; d < 64; d <<= 1) {
            const u32 t = __shfl_up(val, d, 64);
            if (lane >= d) val += t;
        }
        if (lane == 63) wsum[wv] = val;
        __syncthreads();
        u32 woff = 0;
#pragma unroll
        for (int w = 0; w < 4; ++w) if (w < wv) woff += wsum[w];
        val += woff;
        if (tid < SEGPER) { so_l[tid] = so; pre[tid + 1] = val; }
        if (tid == 0) pre[0] = 0;
    }
    __syncthreads();

    const int total = (int)pre[SEGPER];
    // 4 concurrent search+gather+accumulate chains per thread
    for (int base = tid << 2; base < total; base += 1024) {
#pragma unroll
        for (int k = 0; k < 4; ++k) {
            const int i = base + k;
            if (i >= total) break;
            int lo = 0, hi = SEGPER;
            while (hi - lo > 1) {
                const int mid = (lo + hi) >> 1;
                if (pre[mid] <= (u32)i) lo = mid; else hi = mid;
            }
            const int s = sp + lo * SPLIT;
            const u32 p = pairs[(size_t)s * Eb + so_l[lo] + (u32)i - pre[lo]];
            const float val = (float)__builtin_bit_cast(_Float16, (u16)(p & 0xffffu));
            atomicAdd(&acc[p >> 16], val);
        }
    }
    __syncthreads();

    const size_t stride = (size_t)nbuk * RANGE;
    const int node0 = buk * RANGE;
    pf[(size_t)sp * stride + node0 + tid] = acc[tid];
    pf[(size_t)sp * stride + node0 + tid + 256] = acc[tid + 256];
}

__global__ void freduce_kernel(const float* __restrict__ pf, float* __restrict__ f,
                               int n, int stride) {
    const int i = blockIdx.x * 256 + threadIdx.x;
    if (i >= n) return;
    float s = 0.f;
#pragma unroll
    for (int r = 0; r < SPLIT; ++r) s += pf[(size_t)r * stride + i];
    f[i] = s;
}

// ---------------- fallback: direct-atomic path ----------------
__global__ void zero_kernel(float* __restrict__ p, int n) {
    int i = blockIdx.x * blockDim.x + threadIdx.x;
    if (i < n) p[i] = 0.0f;
}

__global__ __launch_bounds__(256) void fb_kernel(
    const float* __restrict__ x,
    const int*   __restrict__ ei,
    const float* __restrict__ u,
    const float* __restrict__ W1, const float* __restrict__ b1,
    const float* __restrict__ W2, const float* __restrict__ b2,
    const float* __restrict__ W3, const float* __restrict__ b3,
    float* __restrict__ f, int E)
{
    const int lane = threadIdx.x & 63;
    const int g    = lane >> 4;
    const int col  = lane & 15;

    Invar v;
    load_invar(v, g, col, W1, b1, W2, b2, W3, b3);

    const int nbatch = E >> 6;
    const int gw = blockIdx.x * 4 + (threadIdx.x >> 6);
    const int nw = gridDim.x * 4;
    for (int bt = gw; bt < nbatch; bt += nw) {
        const int e   = (bt << 6) + lane;
        const int src = ei[e];
        const int dst = ei[E + e];
        const int abpk = pkrtz(x[src], x[dst]);
        const float ud = u[dst];
        const float we = edge_w(v, g, col, abpk);
        atomicAdd(&f[src], we * ud);
    }
}

extern "C" void kernel_launch(void* const* d_in, const int* in_sizes, int n_in,
                              void* d_out, int out_size, void* d_ws, size_t ws_size,
                              hipStream_t stream) {
    const float* x  = (const float*)d_in[0];
    const int*   ei = (const int*)d_in[1];
    const float* u  = (const float*)d_in[2];
    const float* W1 = (const float*)d_in[3];
    const float* b1 = (const float*)d_in[4];
    const float* W2 = (const float*)d_in[5];
    const float* b2 = (const float*)d_in[6];
    const float* W3 = (const float*)d_in[7];
    const float* b3 = (const float*)d_in[8];
    float* f = (float*)d_out;

    const int n = in_sizes[0];
    const int E = in_sizes[1] / 2;

    const int nbuk = (n + RANGE - 1) / RANGE;
    const int Eb = (((E + NSEG - 1) / NSEG) + 63) & ~63;
    const size_t stride = (size_t)nbuk * RANGE;
    const size_t need = ((size_t)NSEG * Eb + (size_t)(nbuk + 1) * NSEG + (size_t)SPLIT * stride)
                        * sizeof(u32);
    const bool xu_fits = (size_t)SPLIT * stride * sizeof(float) >= (size_t)n * sizeof(float2);

    if (nbuk + 1 <= MAXROWS && nbuk <= 256 && Eb <= EBMAX && ws_size >= need
        && (E & 63) == 0 && xu_fits) {
        u32* pairs = (u32*)d_ws;
        u32* offs  = pairs + (size_t)NSEG * Eb;
        float* pf  = (float*)(offs + (size_t)(nbuk + 1) * NSEG);
        float2* xu = (float2*)pf;   // alias: xu dead before p2 writes pf

        xu_pack_kernel<<<(n + 255) / 256, 256, 0, stream>>>(x, u, xu, n);
        p1_kernel<<<NSEG, 256, 0, stream>>>(x, ei, xu, W1, b1, W2, b2, W3, b3,
                                            pairs, offs, E, Eb, nbuk);
        p2_kernel<<<nbuk * SPLIT, 256, 0, stream>>>(pairs, offs, pf, Eb, nbuk);
        freduce_kernel<<<(n + 255) / 256, 256, 0, stream>>>(pf, f, n, (int)stride);
    } else {
        zero_kernel<<<(n + 255) / 256, 256, 0, stream>>>(f, n);
        fb_kernel<<<2048, 256, 0, stream>>>(x, ei, u, W1, b1, W2, b2, W3, b3, f, E);
    }
}

// Round 16
// 127.341 us; speedup vs baseline: 1.1765x; 1.0599x over previous
//
#include <hip/hip_runtime.h>

#define H 32
#define NSEG 1000      // phase-1 segments/blocks
#define RBITS 9
#define RANGE 512      // nodes per bucket = 1<<RBITS
#define SPLIT 10       // phase-2 blocks per bucket
#define SEGPER (NSEG / SPLIT)
#define MAXROWS 260    // max buckets+1 (parallel scan needs nbuk <= 256)
#define EBMAX 6400     // max edges per segment stageable in LDS

typedef __attribute__((ext_vector_type(2))) __fp16 half2v;
typedef __attribute__((ext_vector_type(8))) __fp16 half8;
typedef __attribute__((ext_vector_type(4))) float f32x4;
typedef unsigned int u32;
typedef unsigned short u16;

union HU { int i[4]; half8 h; };

static __device__ __forceinline__ int pkrtz(float a, float b) {
    return __builtin_bit_cast(int, __builtin_amdgcn_cvt_pkrtz(a, b));
}

static __device__ __forceinline__ float fdot2f(int w, int ab, float c) {
    return __builtin_amdgcn_fdot2(__builtin_bit_cast(half2v, w),
                                  __builtin_bit_cast(half2v, ab), c, false);
}

// ---- verified per-edge MLP (R12 structure: fdot2 layer1, MFMA layer2) ----
struct Invar {
    int   w1p[8];
    float b1v[8];
    half8 afrag[2];
    f32x4 c0, c1;                 // b2 slices as MFMA C operand
    float w3lo[4], w3hi[4];
    float b3v;
};

static __device__ __forceinline__ void load_invar(
    Invar& v, int g, int col,
    const float* __restrict__ W1, const float* __restrict__ b1,
    const float* __restrict__ W2, const float* __restrict__ b2,
    const float* __restrict__ W3, const float* __restrict__ b3)
{
    const int klo = 4 * g, khi = 16 + 4 * g;
#pragma unroll
    for (int i = 0; i < 4; ++i) {
        v.w1p[i]     = pkrtz(W1[klo + i], W1[H + klo + i]);
        v.w1p[4 + i] = pkrtz(W1[khi + i], W1[H + khi + i]);
        v.b1v[i]     = b1[klo + i];
        v.b1v[4 + i] = b1[khi + i];
    }
#pragma unroll
    for (int mt = 0; mt < 2; ++mt) {
        HU ua;
        const int c = mt * 16 + col;
        ua.i[0] = pkrtz(W2[(klo + 0) * H + c], W2[(klo + 1) * H + c]);
        ua.i[1] = pkrtz(W2[(klo + 2) * H + c], W2[(klo + 3) * H + c]);
        ua.i[2] = pkrtz(W2[(khi + 0) * H + c], W2[(khi + 1) * H + c]);
        ua.i[3] = pkrtz(W2[(khi + 2) * H + c], W2[(khi + 3) * H + c]);
        v.afrag[mt] = ua.h;
    }
#pragma unroll
    for (int r = 0; r < 4; ++r) {
        v.c0[r] = b2[klo + r]; v.c1[r] = b2[khi + r];
        v.w3lo[r] = W3[klo + r]; v.w3hi[r] = W3[khi + r];
    }
    v.b3v = b3[0];
}

static __device__ __forceinline__ float edge_w(const Invar& v, int g, int col, int abpk)
{
    float wred0 = 0.f, wred1 = 0.f, wred2 = 0.f, wred3 = 0.f;
#pragma unroll
    for (int T = 0; T < 4; ++T) {
        const int abT = __builtin_amdgcn_ds_bpermute(((T << 4) + col) << 2, abpk);
        const float h0 = fmaxf(fdot2f(v.w1p[0], abT, v.b1v[0]), 0.f);
        const float h1 = fmaxf(fdot2f(v.w1p[1], abT, v.b1v[1]), 0.f);
        const float h2 = fmaxf(fdot2f(v.w1p[2], abT, v.b1v[2]), 0.f);
        const float h3 = fmaxf(fdot2f(v.w1p[3], abT, v.b1v[3]), 0.f);
        const float h4 = fmaxf(fdot2f(v.w1p[4], abT, v.b1v[4]), 0.f);
        const float h5 = fmaxf(fdot2f(v.w1p[5], abT, v.b1v[5]), 0.f);
        const float h6 = fmaxf(fdot2f(v.w1p[6], abT, v.b1v[6]), 0.f);
        const float h7 = fmaxf(fdot2f(v.w1p[7], abT, v.b1v[7]), 0.f);

        HU ub;
        ub.i[0] = pkrtz(h0, h1);
        ub.i[1] = pkrtz(h2, h3);
        ub.i[2] = pkrtz(h4, h5);
        ub.i[3] = pkrtz(h6, h7);

        f32x4 acc0 = __builtin_amdgcn_mfma_f32_16x16x32_f16(v.afrag[0], ub.h, v.c0, 0, 0, 0);
        f32x4 acc1 = __builtin_amdgcn_mfma_f32_16x16x32_f16(v.afrag[1], ub.h, v.c1, 0, 0, 0);

        float p = 0.f;
#pragma unroll
        for (int r = 0; r < 4; ++r) {
            p += fmaxf(acc0[r], 0.f) * v.w3lo[r];
            p += fmaxf(acc1[r], 0.f) * v.w3hi[r];
        }
        p += __shfl_xor(p, 16, 64);
        p += __shfl_xor(p, 32, 64);
        const float wt = p + v.b3v;
        if      (T == 0) wred0 = wt;
        else if (T == 1) wred1 = wt;
        else if (T == 2) wred2 = wt;
        else             wred3 = wt;
    }
    const float wa = (g & 1) ? wred1 : wred0;
    const float wb = (g & 1) ? wred3 : wred2;
    return (g & 2) ? wb : wa;
}

// ---------------- xu interleave prep ----------------
__global__ void xu_pack_kernel(const float* __restrict__ x, const float* __restrict__ u,
                               float2* __restrict__ xu, int n) {
    int i = blockIdx.x * 256 + threadIdx.x;
    if (i < n) xu[i] = make_float2(x[i], u[i]);
}

// ---------------- phase 1 (R12-exact: strided offs write, VGPR 64) ----------------
__global__ __launch_bounds__(256) void p1_kernel(
    const float* __restrict__ x,
    const int*   __restrict__ ei,
    const float2* __restrict__ xu,
    const float* __restrict__ W1, const float* __restrict__ b1,
    const float* __restrict__ W2, const float* __restrict__ b2,
    const float* __restrict__ W3, const float* __restrict__ b3,
    u32* __restrict__ pairs, u32* __restrict__ offs,
    int E, int Eb, int nbuk)
{
    __shared__ u32 cnt[MAXROWS];
    __shared__ u32 cur[MAXROWS];
    __shared__ u32 wsum[4];
    __shared__ u32 lds_pairs[EBMAX];
    const int tid  = threadIdx.x;
    const int lane = tid & 63;
    const int wv   = tid >> 6;
    const int g    = lane >> 4;
    const int col  = lane & 15;
    const int b    = blockIdx.x;

    const int slice0 = b * Eb;
    int sliceN = E - slice0;
    if (sliceN < 0) sliceN = 0;
    if (sliceN > Eb) sliceN = Eb;

    Invar v;
    load_invar(v, g, col, W1, b1, W2, b2, W3, b3);

    for (int k = tid; k <= nbuk; k += 256) cnt[k] = 0;
    __syncthreads();
    if (((slice0 & 3) == 0) && ((sliceN & 3) == 0)) {
        const uint4* e4 = (const uint4*)(ei + slice0);
        const int n4 = sliceN >> 2;
        for (int i = tid; i < n4; i += 256) {
            const uint4 s4 = e4[i];
            atomicAdd(&cnt[s4.x >> RBITS], 1u);
            atomicAdd(&cnt[s4.y >> RBITS], 1u);
            atomicAdd(&cnt[s4.z >> RBITS], 1u);
            atomicAdd(&cnt[s4.w >> RBITS], 1u);
        }
    } else {
        for (int i = tid; i < sliceN; i += 256)
            atomicAdd(&cnt[((u32)ei[slice0 + i]) >> RBITS], 1u);
    }
    __syncthreads();

    // parallel exclusive scan over nbuk (<=256) bins
    {
        const u32 myc = (tid < nbuk) ? cnt[tid] : 0;
        u32 val = myc;
#pragma unroll
        for (int d = 1; d < 64; d <<= 1) {
            const u32 t = __shfl_up(val, d, 64);
            if (lane >= d) val += t;
        }
        if (lane == 63) wsum[wv] = val;
        __syncthreads();
        u32 woff = 0;
#pragma unroll
        for (int w = 0; w < 4; ++w) if (w < wv) woff += wsum[w];
        val += woff;
        if (tid < nbuk) cur[tid] = val - myc;
        if (tid == 0)   cur[nbuk] = wsum[0] + wsum[1] + wsum[2] + wsum[3];
    }
    __syncthreads();
    // R12 layout: offs[k*NSEG + b] (keeps p1 at 64 VGPR)
    for (int k = tid; k <= nbuk; k += 256) offs[(size_t)k * NSEG + b] = cur[k];
    __syncthreads();

    // pass B: MLP + bucket-sorted scatter into LDS; 4 groups per wave-iteration
    const int nbfull = sliceN >> 6;
    const int nquad  = nbfull >> 2;
    for (int q = wv; q < nquad; q += 4) {
        const int e0 = slice0 + (q << 8) + lane;
        const int e1 = e0 + 64, e2 = e0 + 128, e3 = e0 + 192;
        const int src0 = ei[e0],     src1 = ei[e1],     src2 = ei[e2],     src3 = ei[e3];
        const int dst0 = ei[E + e0], dst1 = ei[E + e1], dst2 = ei[E + e2], dst3 = ei[E + e3];
        const float  x0  = x[src0],  x1  = x[src1],  x2  = x[src2],  x3  = x[src3];
        const float2 xd0 = xu[dst0], xd1 = xu[dst1], xd2 = xu[dst2], xd3 = xu[dst3];

        const float w0 = edge_w(v, g, col, pkrtz(x0, xd0.x));
        const float w1 = edge_w(v, g, col, pkrtz(x1, xd1.x));
        const float w2 = edge_w(v, g, col, pkrtz(x2, xd2.x));
        const float w3 = edge_w(v, g, col, pkrtz(x3, xd3.x));

        const u32 pos0 = atomicAdd(&cur[((u32)src0) >> RBITS], 1u);
        lds_pairs[pos0] = ((u32)(u16)pkrtz(w0 * xd0.y, 0.0f)) | (((u32)src0 & (RANGE - 1)) << 16);
        const u32 pos1 = atomicAdd(&cur[((u32)src1) >> RBITS], 1u);
        lds_pairs[pos1] = ((u32)(u16)pkrtz(w1 * xd1.y, 0.0f)) | (((u32)src1 & (RANGE - 1)) << 16);
        const u32 pos2 = atomicAdd(&cur[((u32)src2) >> RBITS], 1u);
        lds_pairs[pos2] = ((u32)(u16)pkrtz(w2 * xd2.y, 0.0f)) | (((u32)src2 & (RANGE - 1)) << 16);
        const u32 pos3 = atomicAdd(&cur[((u32)src3) >> RBITS], 1u);
        lds_pairs[pos3] = ((u32)(u16)pkrtz(w3 * xd3.y, 0.0f)) | (((u32)src3 & (RANGE - 1)) << 16);
    }
    const int nbany = (sliceN + 63) >> 6;
    for (int bi = (nquad << 2) + wv; bi < nbany; bi += 4) {
        const int loc = (bi << 6) + lane;
        const bool valid = loc < sliceN;
        const int eL = slice0 + (valid ? loc : 0);
        const int src = ei[eL];
        const int dst = ei[E + eL];
        const float2 xud = xu[dst];
        const int abpk = pkrtz(x[src], xud.x);
        const float we = edge_w(v, g, col, abpk);
        if (valid) {
            const int buk = ((u32)src) >> RBITS;
            const u32 pos = atomicAdd(&cur[buk], 1u);
            lds_pairs[pos] = ((u32)(u16)pkrtz(we * xud.y, 0.0f)) | (((u32)src & (RANGE - 1)) << 16);
        }
    }
    __syncthreads();

    const int n4 = sliceN >> 2;
    const uint4* lp4 = (const uint4*)lds_pairs;
    uint4* gp4 = (uint4*)(pairs + slice0);
    for (int i = tid; i < n4; i += 256) gp4[i] = lp4[i];
    for (int i = (n4 << 2) + tid; i < sliceN; i += 256) pairs[slice0 + i] = lds_pairs[i];
}

// ---------------- phase 2: flat-indexed per-bucket LDS accumulate ----------------
__global__ __launch_bounds__(256) void p2_kernel(
    const u32* __restrict__ pairs, const u32* __restrict__ offs,
    float* __restrict__ pf, int Eb, int nbuk)
{
    __shared__ float acc[RANGE];
    __shared__ u32 so_l[SEGPER];
    __shared__ u32 pre[SEGPER + 1];
    __shared__ u32 wsum[4];
    const int tid = threadIdx.x;
    const int lane = tid & 63;
    const int wv  = tid >> 6;
    const int buk = blockIdx.x / SPLIT;
    const int sp  = blockIdx.x % SPLIT;

    acc[tid] = 0.f;
    acc[tid + 256] = 0.f;
    u32 myc = 0, so = 0;
    if (tid < SEGPER) {
        const int s = sp + tid * SPLIT;
        so  = offs[(size_t)buk * NSEG + s];
        myc = offs[(size_t)(buk + 1) * NSEG + s] - so;
    }
    {
        u32 val = myc;
#pragma unroll
        for (int d = 1; d < 64; d <<= 1) {
            const u32 t = __shfl_up(val, d, 64);
            if (lane >= d) val += t;
        }
        if (lane == 63) wsum[wv] = val;
        __syncthreads();
        u32 woff = 0;
#pragma unroll
        for (int w = 0; w < 4; ++w) if (w < wv) woff += wsum[w];
        val += woff;
        if (tid < SEGPER) { so_l[tid] = so; pre[tid + 1] = val; }
        if (tid == 0) pre[0] = 0;
    }
    __syncthreads();

    const int total = (int)pre[SEGPER];
    // 4 concurrent search+gather+accumulate chains per thread
    for (int base = tid << 2; base < total; base += 1024) {
#pragma unroll
        for (int k = 0; k < 4; ++k) {
            const int i = base + k;
            if (i >= total) break;
            int lo = 0, hi = SEGPER;
            while (hi - lo > 1) {
                const int mid = (lo + hi) >> 1;
                if (pre[mid] <= (u32)i) lo = mid; else hi = mid;
            }
            const int s = sp + lo * SPLIT;
            const u32 p = pairs[(size_t)s * Eb + so_l[lo] + (u32)i - pre[lo]];
            const float val = (float)__builtin_bit_cast(_Float16, (u16)(p & 0xffffu));
            atomicAdd(&acc[p >> 16], val);
        }
    }
    __syncthreads();

    const size_t stride = (size_t)nbuk * RANGE;
    const int node0 = buk * RANGE;
    pf[(size_t)sp * stride + node0 + tid] = acc[tid];
    pf[(size_t)sp * stride + node0 + tid + 256] = acc[tid + 256];
}

__global__ void freduce_kernel(const float* __restrict__ pf, float* __restrict__ f,
                               int n, int stride) {
    const int i = blockIdx.x * 256 + threadIdx.x;
    if (i >= n) return;
    float s = 0.f;
#pragma unroll
    for (int r = 0; r < SPLIT; ++r) s += pf[(size_t)r * stride + i];
    f[i] = s;
}

// ---------------- fallback: direct-atomic path ----------------
__global__ void zero_kernel(float* __restrict__ p, int n) {
    int i = blockIdx.x * blockDim.x + threadIdx.x;
    if (i < n) p[i] = 0.0f;
}

__global__ __launch_bounds__(256) void fb_kernel(
    const float* __restrict__ x,
    const int*   __restrict__ ei,
    const float* __restrict__ u,
    const float* __restrict__ W1, const float* __restrict__ b1,
    const float* __restrict__ W2, const float* __restrict__ b2,
    const float* __restrict__ W3, const float* __restrict__ b3,
    float* __restrict__ f, int E)
{
    const int lane = threadIdx.x & 63;
    const int g    = lane >> 4;
    const int col  = lane & 15;

    Invar v;
    load_invar(v, g, col, W1, b1, W2, b2, W3, b3);

    const int nbatch = E >> 6;
    const int gw = blockIdx.x * 4 + (threadIdx.x >> 6);
    const int nw = gridDim.x * 4;
    for (int bt = gw; bt < nbatch; bt += nw) {
        const int e   = (bt << 6) + lane;
        const int src = ei[e];
        const int dst = ei[E + e];
        const int abpk = pkrtz(x[src], x[dst]);
        const float ud = u[dst];
        const float we = edge_w(v, g, col, abpk);
        atomicAdd(&f[src], we * ud);
    }
}

extern "C" void kernel_launch(void* const* d_in, const int* in_sizes, int n_in,
                              void* d_out, int out_size, void* d_ws, size_t ws_size,
                              hipStream_t stream) {
    const float* x  = (const float*)d_in[0];
    const int*   ei = (const int*)d_in[1];
    const float* u  = (const float*)d_in[2];
    const float* W1 = (const float*)d_in[3];
    const float* b1 = (const float*)d_in[4];
    const float* W2 = (const float*)d_in[5];
    const float* b2 = (const float*)d_in[6];
    const float* W3 = (const float*)d_in[7];
    const float* b3 = (const float*)d_in[8];
    float* f = (float*)d_out;

    const int n = in_sizes[0];
    const int E = in_sizes[1] / 2;

    const int nbuk = (n + RANGE - 1) / RANGE;
    const int Eb = (((E + NSEG - 1) / NSEG) + 63) & ~63;
    const size_t stride = (size_t)nbuk * RANGE;
    const size_t need = ((size_t)NSEG * Eb + (size_t)(nbuk + 1) * NSEG + (size_t)SPLIT * stride)
                        * sizeof(u32);
    const bool xu_fits = (size_t)SPLIT * stride * sizeof(float) >= (size_t)n * sizeof(float2);

    if (nbuk + 1 <= MAXROWS && nbuk <= 256 && Eb <= EBMAX && ws_size >= need
        && (E & 63) == 0 && xu_fits) {
        u32* pairs = (u32*)d_ws;
        u32* offs  = pairs + (size_t)NSEG * Eb;
        float* pf  = (float*)(offs + (size_t)(nbuk + 1) * NSEG);
        float2* xu = (float2*)pf;   // alias: xu dead before p2 writes pf

        xu_pack_kernel<<<(n + 255) / 256, 256, 0, stream>>>(x, u, xu, n);
        p1_kernel<<<NSEG, 256, 0, stream>>>(x, ei, xu, W1, b1, W2, b2, W3, b3,
                                            pairs, offs, E, Eb, nbuk);
        p2_kernel<<<nbuk * SPLIT, 256, 0, stream>>>(pairs, offs, pf, Eb, nbuk);
        freduce_kernel<<<(n + 255) / 256, 256, 0, stream>>>(pf, f, n, (int)stride);
    } else {
        zero_kernel<<<(n + 255) / 256, 256, 0, stream>>>(f, n);
        fb_kernel<<<2048, 256, 0, stream>>>(x, ei, u, W1, b1, W2, b2, W3, b3, f, E);
    }
}